// Round 5
// baseline (38669.980 us; speedup 1.0000x reference)
//
#include <hip/hip_runtime.h>
#include <stdint.h>

// Problem dims
#define B_    64
#define T_    2048
#define IN_   64
#define H_    512
#define H2_   1024
#define OUT_  32
#define KTOT  576          // IN_ + H_

// Grid: 128 blocks = 8 batch-groups x 16 block-halves, 512 threads.
// Each block fuses TWO of the old 256-thread col-group engines (sub = tid>>8,
// vcg = 2*cgh + sub): same per-thread work/registers, but barrier fan-in,
// counter contention and poll traffic all halve vs the 256-block layout.
#define NBG   8
#define NCGH  16           // block-halves per bg (16 blocks x 2 subs = 32 vcg)
#define NTHR  512
#define BPG   8            // batches per group
#define KSL   18           // k per slice (32 slices x 18 = 576)
#define RS    12           // bufA row stride in floats

// ws layout (32-bit words)
// Barriers: one aggregated u32 counter per (bg, phase), 4KB-strided so the 16
// hot words map to distinct channels (round-4 win). Fan-in now 16 adds.
#define ABORT_IDX   0
#define CTR_OFF     1024                 // first counter, word offset (4KB)
#define CTR_STRIDE  1024                 // 4KB between counters
#define NCTR        (NBG * 2)            // 16 counters
#define BUF_BASE    (CTR_OFF + NCTR * CTR_STRIDE)   // 17408 (64B-aligned)
#define XSLAB       32768    // words per slab: [8 bg][512 j][8 b]

// ---- MALL-resident exchange primitives ----
// Publish TWO adjacent floats as one 8B atomic swap (sc1 -> executed AT the
// MALL; line stays MALL-dirty). NO trailing drain here: the drain is done
// once, after independent work (y-matmul / u-prefetch), just before the
// counter bump -- hiding the round trip.
__device__ __forceinline__ void gpub2f(float* p, float v0, float v1) {
  unsigned long long q =
      ((unsigned long long)__float_as_uint(v1) << 32) |
      (unsigned long long)__float_as_uint(v0);
  asm volatile("global_atomic_swap_x2 %0, %1, off sc1"
               :: "v"(p), "v"(q) : "memory");
}
// Counter bump: fire-and-forget one-way add at the MALL.
__device__ __forceinline__ void gaddu(unsigned* p, unsigned v) {
  asm volatile("global_atomic_add %0, %1, off sc1"
               :: "v"(p), "v"(v) : "memory");
}
// Coherent 4B poll load (bypasses stale L1/L2, reads the MALL).
__device__ __forceinline__ unsigned gpollu(const unsigned* p) {
  unsigned v;
  asm volatile("global_load_dword %0, %1, off sc0 sc1\n\ts_waitcnt vmcnt(0)"
               : "=v"(v) : "v"(p) : "memory");
  return v;
}
// Consume: MALL-coherent 16B loads, 2 in flight, one wait (8 floats/thread;
// 512 threads cover the whole 512x8 slab).
__device__ __forceinline__ void gload2(const float* p0, const float* p1,
                                       float4& a, float4& b) {
  asm volatile(
      "global_load_dwordx4 %0, %2, off sc0 sc1\n\t"
      "global_load_dwordx4 %1, %3, off sc0 sc1\n\t"
      "s_waitcnt vmcnt(0)"
      : "=&v"(a), "=&v"(b)
      : "v"(p0), "v"(p1)
      : "memory");
}

__global__ __launch_bounds__(256) void gru_init(float* ws, const float* __restrict__ x0) {
  int i = blockIdx.x * blockDim.x + threadIdx.x;
  int stride = gridDim.x * blockDim.x;
  unsigned* w = (unsigned*)ws;
  for (int k = i; k < BUF_BASE; k += stride) w[k] = 0u;   // abort + counters
  // xg0[bg][j][b] = x0[(bg*8+b)*512 + j]
  for (int k = i; k < NBG * H_ * BPG; k += stride) {
    int bg = k >> 12, j = (k >> 3) & (H_ - 1), b = k & 7;
    ws[BUF_BASE + k] = x0[(bg * 8 + b) * H_ + j];
  }
}

// Wait: ONE lane polls ONE 4KB-isolated counter word until it reaches target.
__device__ __forceinline__ bool gbar_wait(unsigned* ctr, unsigned target,
                                          unsigned* abort_w) {
  __shared__ int s_ok;
  if (threadIdx.x == 0) {
    int ok = 1;
    int polls = 0;
    while (gpollu(ctr) < target) {
      __builtin_amdgcn_s_sleep(1);
      if ((++polls & 255) == 0) {
        if (__hip_atomic_load(abort_w, __ATOMIC_RELAXED, __HIP_MEMORY_SCOPE_AGENT) != 0u ||
            polls > 2000000) {
          __hip_atomic_store(abort_w, 1u, __ATOMIC_RELAXED, __HIP_MEMORY_SCOPE_AGENT);
          ok = 0;
          break;
        }
      }
    }
    s_ok = ok;
  }
  __syncthreads();
  __atomic_signal_fence(__ATOMIC_ACQUIRE);  // compiler reordering guard only
  return s_ok != 0;
}

__global__ __launch_bounds__(NTHR, 1) void gru_main(
    const float* __restrict__ u, const float* __restrict__ kfz,
    const float* __restrict__ bfz, const float* __restrict__ kr,
    const float* __restrict__ br, const float* __restrict__ wout,
    const float* __restrict__ bout, float* __restrict__ out, float* ws) {
  unsigned* wsu = (unsigned*)ws;
  unsigned* abort_w = wsu + ABORT_IDX;
  float* xg0 = ws + BUF_BASE;
  float* xg1 = xg0 + XSLAB;
  float* xfg = xg1 + XSLAB;

  const int bg   = blockIdx.x & 7;
  const int cgh  = blockIdx.x >> 3;   // block-half group 0..15
  const int tid  = threadIdx.x;       // 0..511
  const int sub  = tid >> 8;          // virtual engine 0/1
  const int vtid = tid & 255;         // thread within virtual engine
  const int vcg  = cgh * 2 + sub;     // column group 0..31
  const int w    = vtid >> 6;         // wave-in-engine 0..3
  const int l    = vtid & 63;
  const int cq   = l & 7;             // col-quad 0..7
  const int g    = l >> 3;            // in-wave k-slice 0..7
  const int kb   = (w * 8 + g) * KSL; // this thread's k base (18 k's)
  const int prow = (vtid & 127) >> 2; // finalize col 0..31 (vtid<128)
  const int b0   = (vtid & 3) * 2;    // finalize batch pair base
  const int fcB  = vtid >> 3;         // tanh col 0..15 (vtid<128)
  const int fbB  = vtid & 7;          // tanh batch
  const int yb   = vtid >> 5;         // y batch 0..7
  const int yq   = vtid & 31;         // y k-slice 0..31

  unsigned* ctrA = wsu + CTR_OFF + (bg * 2 + 0) * CTR_STRIDE;
  unsigned* ctrB = wsu + CTR_OFF + (bg * 2 + 1) * CTR_STRIDE;

  __shared__ float bufA[KTOT * RS];   // [k][12]: u_t(k<64) | x or f*x
  __shared__ float pA[2][4 * 32 * RS];
  __shared__ float pB[2][4 * 16 * RS];
  __shared__ float rbuf[2][16 * 8];
  float* pAs = pA[sub];
  float* pBs = pB[sub];
  float* rbs = rbuf[sub];

  // ---- one-time: weights into registers ----
  float wA[KSL][4];
#pragma unroll
  for (int i = 0; i < KSL; ++i)
#pragma unroll
    for (int m = 0; m < 4; ++m) {
      int c = 4 * cq + m;
      int gcol = (c < 16) ? (16 * vcg + c) : (512 + 16 * vcg + (c - 16));
      wA[i][m] = kfz[(size_t)(kb + i) * H2_ + gcol];
    }
  float wB[KSL][2];
#pragma unroll
  for (int i = 0; i < KSL; ++i)
#pragma unroll
    for (int m = 0; m < 2; ++m)
      wB[i][m] = kr[(size_t)(kb + i) * H_ + (16 * vcg + 2 * cq + m)];
  float wy[16];
#pragma unroll
  for (int i = 0; i < 16; ++i) wy[i] = wout[vcg * H_ + (yq + 32 * i)];
  const float by = bout[vcg];
  const int fzc = (prow < 16) ? (16 * vcg + prow) : (512 + 16 * vcg + (prow - 16));
  const float biasA = ((vtid & 255) < 128) ? bfz[fzc] : 0.0f;
  const float biasB = (vtid < 128) ? br[16 * vcg + fcB] : 0.0f;

  float zreg0 = 0.0f, zreg1 = 0.0f, xoldz0 = 0.0f, xoldz1 = 0.0f;

  // u_t=0 into LDS (later steps prefetched during the barrier-B window)
  if (tid < 256) {
    int k2 = tid & 31, b = tid >> 5;
    float2 uv = *(const float2*)&u[((size_t)(bg * 8 + b) * T_) * IN_ + 2 * k2];
    bufA[(2 * k2) * RS + b] = uv.x;
    bufA[(2 * k2 + 1) * RS + b] = uv.y;
  }

  for (int t = 0; t < T_; ++t) {
    float* xcur = (t & 1) ? xg1 : xg0;
    float* xnxt = (t & 1) ? xg0 : xg1;

    // ---- stage x into bufA: 512 threads, 1 row of 8 floats each ----
    {
      const float* s0 = &xcur[(size_t)(bg * H_ + tid) * 8];
      float4 a, b;
      gload2(s0, s0 + 4, a, b);
      *(float4*)&bufA[(64 + tid) * RS] = a;
      *(float4*)&bufA[(64 + tid) * RS + 4] = b;
    }
    __syncthreads();

    // ---- phase A core: fz partials for 4 cols x 8 batches over 18 k ----
    float acc[4][8] = {};
#pragma unroll
    for (int i = 0; i < KSL; ++i) {
      const float* xr = &bufA[(kb + i) * RS];
      float4 x0 = *(const float4*)xr;
      float4 x1 = *(const float4*)(xr + 4);
#pragma unroll
      for (int m = 0; m < 4; ++m) {
        float wv = wA[i][m];
        acc[m][0] += wv * x0.x; acc[m][1] += wv * x0.y;
        acc[m][2] += wv * x0.z; acc[m][3] += wv * x0.w;
        acc[m][4] += wv * x1.x; acc[m][5] += wv * x1.y;
        acc[m][6] += wv * x1.z; acc[m][7] += wv * x1.w;
      }
    }

    // ---- reduce A (within each 64-lane wave) ----
#pragma unroll
    for (int m = 0; m < 4; ++m)
#pragma unroll
      for (int b = 0; b < 8; ++b) {
        acc[m][b] += __shfl_xor(acc[m][b], 8);
        acc[m][b] += __shfl_xor(acc[m][b], 16);
        acc[m][b] += __shfl_xor(acc[m][b], 32);
      }
    if (g == 0) {
#pragma unroll
      for (int m = 0; m < 4; ++m) {
        float* p = &pAs[(w * 32 + 4 * cq + m) * RS];
        *(float4*)p = make_float4(acc[m][0], acc[m][1], acc[m][2], acc[m][3]);
        *(float4*)(p + 4) = make_float4(acc[m][4], acc[m][5], acc[m][6], acc[m][7]);
      }
    }
    __syncthreads();

    // ---- finalize A: sigmoid pairs; packed f*x publish (no drain yet) ----
    if (vtid < 128) {
      float s0 = pAs[(0 * 32 + prow) * RS + b0] + pAs[(1 * 32 + prow) * RS + b0] +
                 pAs[(2 * 32 + prow) * RS + b0] + pAs[(3 * 32 + prow) * RS + b0] + biasA;
      float s1 = pAs[(0 * 32 + prow) * RS + b0 + 1] + pAs[(1 * 32 + prow) * RS + b0 + 1] +
                 pAs[(2 * 32 + prow) * RS + b0 + 1] + pAs[(3 * 32 + prow) * RS + b0 + 1] + biasA;
      float sig0 = 1.0f / (1.0f + __expf(-s0));
      float sig1 = 1.0f / (1.0f + __expf(-s1));
      if (prow < 16) {
        int col = 16 * vcg + prow;
        float xo0 = bufA[(64 + col) * RS + b0];
        float xo1 = bufA[(64 + col) * RS + b0 + 1];
        gpub2f(&xfg[((size_t)bg * H_ + col) * 8 + b0], sig0 * xo0, sig1 * xo1);
      } else {
        int col = 16 * vcg + (prow - 16);
        zreg0 = sig0; zreg1 = sig1;
        xoldz0 = bufA[(64 + col) * RS + b0];
        xoldz1 = bufA[(64 + col) * RS + b0 + 1];
      }
    }

    // ---- y_t = x_t @ wout[vcg]: covers the publish drain ----
    float yp = 0.0f;
    {
#pragma unroll
      for (int i = 0; i < 16; ++i)
        yp += wy[i] * bufA[(64 + yq + 32 * i) * RS + yb];
      yp += __shfl_xor(yp, 1);  yp += __shfl_xor(yp, 2);
      yp += __shfl_xor(yp, 4);  yp += __shfl_xor(yp, 8);
      yp += __shfl_xor(yp, 16);
    }

    // drain publishes -> block sync -> one counter bump
    asm volatile("s_waitcnt vmcnt(0)" ::: "memory");
    __syncthreads();
    if (tid == 0) gaddu(ctrA, 1u);

    // out-store overlaps the barrier poll
    if (yq == 0)
      out[((size_t)(bg * 8 + yb) * T_ + t) * OUT_ + vcg] = yp + by;

    if (!gbar_wait(ctrA, (unsigned)(NCGH * (t + 1)), abort_w)) return;

    // ---- stage f*x into bufA ----
    {
      const float* s0 = &xfg[(size_t)(bg * H_ + tid) * 8];
      float4 a, b;
      gload2(s0, s0 + 4, a, b);
      *(float4*)&bufA[(64 + tid) * RS] = a;
      *(float4*)&bufA[(64 + tid) * RS + 4] = b;
    }
    __syncthreads();

    // ---- phase B core: r partials for 2 cols x 8 batches ----
    float acc2[2][8] = {};
#pragma unroll
    for (int i = 0; i < KSL; ++i) {
      const float* xr = &bufA[(kb + i) * RS];
      float4 x0 = *(const float4*)xr;
      float4 x1 = *(const float4*)(xr + 4);
#pragma unroll
      for (int m = 0; m < 2; ++m) {
        float wv = wB[i][m];
        acc2[m][0] += wv * x0.x; acc2[m][1] += wv * x0.y;
        acc2[m][2] += wv * x0.z; acc2[m][3] += wv * x0.w;
        acc2[m][4] += wv * x1.x; acc2[m][5] += wv * x1.y;
        acc2[m][6] += wv * x1.z; acc2[m][7] += wv * x1.w;
      }
    }
#pragma unroll
    for (int m = 0; m < 2; ++m)
#pragma unroll
      for (int b = 0; b < 8; ++b) {
        acc2[m][b] += __shfl_xor(acc2[m][b], 8);
        acc2[m][b] += __shfl_xor(acc2[m][b], 16);
        acc2[m][b] += __shfl_xor(acc2[m][b], 32);
      }
    if (g == 0) {
#pragma unroll
      for (int m = 0; m < 2; ++m) {
        float* p = &pBs[(w * 16 + 2 * cq + m) * RS];
        *(float4*)p = make_float4(acc2[m][0], acc2[m][1], acc2[m][2], acc2[m][3]);
        *(float4*)(p + 4) = make_float4(acc2[m][4], acc2[m][5], acc2[m][6], acc2[m][7]);
      }
    }
    __syncthreads();

    // ---- finalize B: tanh -> rbuf ----
    if (vtid < 128) {
      float s = pBs[(0 * 16 + fcB) * RS + fbB] + pBs[(1 * 16 + fcB) * RS + fbB] +
                pBs[(2 * 16 + fcB) * RS + fbB] + pBs[(3 * 16 + fcB) * RS + fbB] + biasB;
      float e = __expf(2.0f * s);
      rbs[fcB * 8 + fbB] = 1.0f - 2.0f / (1.0f + e);
    }
    __syncthreads();

    // ---- update: packed x_next publish (no drain yet) ----
    if (vtid >= 64 && vtid < 128) {
      int zr = prow - 16;   // 0..15
      float r0 = rbs[zr * 8 + b0];
      float r1 = rbs[zr * 8 + b0 + 1];
      float xn0 = xoldz0 + zreg0 * (r0 - xoldz0);
      float xn1 = xoldz1 + zreg1 * (r1 - xoldz1);
      gpub2f(&xnxt[((size_t)bg * H_ + 16 * vcg + zr) * 8 + b0], xn0, xn1);
    }

    // ---- prefetch u_{t+1} into LDS: covers the publish drain ----
    if (tid < 256 && t + 1 < T_) {
      int k2 = tid & 31, b = tid >> 5;
      float2 uv = *(const float2*)&u[((size_t)(bg * 8 + b) * T_ + (t + 1)) * IN_ + 2 * k2];
      bufA[(2 * k2) * RS + b] = uv.x;
      bufA[(2 * k2 + 1) * RS + b] = uv.y;
    }

    asm volatile("s_waitcnt vmcnt(0)" ::: "memory");
    __syncthreads();
    if (tid == 0) gaddu(ctrB, 1u);

    if (!gbar_wait(ctrB, (unsigned)(NCGH * (t + 1)), abort_w)) return;
  }
}

extern "C" void kernel_launch(void* const* d_in, const int* in_sizes, int n_in,
                              void* d_out, int out_size, void* d_ws, size_t ws_size,
                              hipStream_t stream) {
  const float* u    = (const float*)d_in[0];
  const float* x0   = (const float*)d_in[1];
  const float* kfz  = (const float*)d_in[2];
  const float* bfz  = (const float*)d_in[3];
  const float* kr   = (const float*)d_in[4];
  const float* br   = (const float*)d_in[5];
  const float* wout = (const float*)d_in[6];
  const float* bout = (const float*)d_in[7];
  float* out = (float*)d_out;
  float* ws  = (float*)d_ws;

  hipLaunchKernelGGL(gru_init, dim3(64), dim3(256), 0, stream, ws, x0);
  hipLaunchKernelGGL(gru_main, dim3(NBG * NCGH), dim3(NTHR), 0, stream,
                     u, kfz, bfz, kr, br, wout, bout, out, ws);
}

// Round 6
// 15610.365 us; speedup vs baseline: 2.4772x; 2.4772x over previous
//
#include <hip/hip_runtime.h>
#include <stdint.h>

// Problem dims
#define B_    64
#define T_    2048
#define IN_   64
#define H_    512
#define H2_   1024
#define OUT_  32
#define KTOT  576          // IN_ + H_

// Grid: 256 blocks = 8 batch-groups x 32 col-groups, 256 threads.
// (512-thread fusion FAILED in round 5: VGPR cap 128 -> weight spill -> 4.7GB
// scratch traffic. 256 threads @ ~196 VGPR is a hard design constraint.)
#define NBG   8
#define NCG   32
#define NTHR  256
#define BPG   8            // batches per group
#define KSL   18           // k per slice (32 slices x 18 = 576)
#define RS    12           // bufA row stride in floats

// ws layout (32-bit words)
// Barriers: one aggregated u32 counter per (bg, phase), 4KB-strided so the 16
// hot words map to distinct channels (round-4 win: 15.3 -> 13.9 ms).
#define ABORT_IDX   0
#define CTR_OFF     1024                 // first counter, word offset (4KB)
#define CTR_STRIDE  1024                 // 4KB between counters
#define NCTR        (NBG * 2)            // 16 counters
#define BUF_BASE    (CTR_OFF + NCTR * CTR_STRIDE)   // 17408 (64B-aligned)
#define XSLAB       32768    // words per slab: [8 bg][512 j][8 b]

// ---- MALL-resident exchange primitives ----
// Publish TWO adjacent floats as one 8B atomic swap (sc1 -> executed AT the
// MALL; line stays MALL-dirty, not written through to HBM). Fire-and-forget:
// the single drain happens later, after independent work (y-matmul or
// u-prefetch), just before the counter bump -- hiding the round trip.
__device__ __forceinline__ void gpub2f(float* p, float v0, float v1) {
  unsigned long long q =
      ((unsigned long long)__float_as_uint(v1) << 32) |
      (unsigned long long)__float_as_uint(v0);
  asm volatile("global_atomic_swap_x2 %0, %1, off sc1"
               :: "v"(p), "v"(q) : "memory");
}
// Counter bump: fire-and-forget one-way add at the MALL.
__device__ __forceinline__ void gaddu(unsigned* p, unsigned v) {
  asm volatile("global_atomic_add %0, %1, off sc1"
               :: "v"(p), "v"(v) : "memory");
}
// Coherent 4B poll load (bypasses stale L1/L2, reads the MALL).
__device__ __forceinline__ unsigned gpollu(const unsigned* p) {
  unsigned v;
  asm volatile("global_load_dword %0, %1, off sc0 sc1\n\ts_waitcnt vmcnt(0)"
               : "=v"(v) : "v"(p) : "memory");
  return v;
}
// Consume: MALL-coherent 16B loads, 4 in flight, one wait -> one latency
// exposure for the whole 32B-per-region stage.
__device__ __forceinline__ void gload4x4(const float* p0, const float* p1,
                                         const float* p2, const float* p3,
                                         float4& a, float4& b, float4& c, float4& d) {
  asm volatile(
      "global_load_dwordx4 %0, %4, off sc0 sc1\n\t"
      "global_load_dwordx4 %1, %5, off sc0 sc1\n\t"
      "global_load_dwordx4 %2, %6, off sc0 sc1\n\t"
      "global_load_dwordx4 %3, %7, off sc0 sc1\n\t"
      "s_waitcnt vmcnt(0)"
      : "=&v"(a), "=&v"(b), "=&v"(c), "=&v"(d)
      : "v"(p0), "v"(p1), "v"(p2), "v"(p3)
      : "memory");
}

__global__ __launch_bounds__(256) void gru_init(float* ws, const float* __restrict__ x0) {
  int i = blockIdx.x * blockDim.x + threadIdx.x;
  int stride = gridDim.x * blockDim.x;
  unsigned* w = (unsigned*)ws;
  for (int k = i; k < BUF_BASE; k += stride) w[k] = 0u;   // abort + counters
  // xg0[bg][j][b] = x0[(bg*8+b)*512 + j]
  for (int k = i; k < NBG * H_ * BPG; k += stride) {
    int bg = k >> 12, j = (k >> 3) & (H_ - 1), b = k & 7;
    ws[BUF_BASE + k] = x0[(bg * 8 + b) * H_ + j];
  }
}

// Wait: ONE lane polls ONE 4KB-isolated counter word until it reaches target.
__device__ __forceinline__ bool gbar_wait(unsigned* ctr, unsigned target,
                                          unsigned* abort_w) {
  __shared__ int s_ok;
  if (threadIdx.x == 0) {
    int ok = 1;
    int polls = 0;
    while (gpollu(ctr) < target) {
      __builtin_amdgcn_s_sleep(1);
      if ((++polls & 255) == 0) {
        if (__hip_atomic_load(abort_w, __ATOMIC_RELAXED, __HIP_MEMORY_SCOPE_AGENT) != 0u ||
            polls > 2000000) {
          __hip_atomic_store(abort_w, 1u, __ATOMIC_RELAXED, __HIP_MEMORY_SCOPE_AGENT);
          ok = 0;
          break;
        }
      }
    }
    s_ok = ok;
  }
  __syncthreads();
  __atomic_signal_fence(__ATOMIC_ACQUIRE);  // compiler reordering guard only
  return s_ok != 0;
}

__global__ __launch_bounds__(NTHR, 1) void gru_main(
    const float* __restrict__ u, const float* __restrict__ kfz,
    const float* __restrict__ bfz, const float* __restrict__ kr,
    const float* __restrict__ br, const float* __restrict__ wout,
    const float* __restrict__ bout, float* __restrict__ out, float* ws) {
  unsigned* wsu = (unsigned*)ws;
  unsigned* abort_w = wsu + ABORT_IDX;
  float* xg0 = ws + BUF_BASE;
  float* xg1 = xg0 + XSLAB;
  float* xfg = xg1 + XSLAB;

  const int bg  = blockIdx.x & 7;
  const int cg  = blockIdx.x >> 3;   // column group 0..31
  const int tid = threadIdx.x;
  const int w   = tid >> 6;          // wave 0..3
  const int l   = tid & 63;
  const int cq  = l & 7;             // col-quad 0..7
  const int g   = l >> 3;            // in-wave k-slice 0..7
  const int kb  = (w * 8 + g) * KSL; // this thread's k base (18 k's)
  const int prow = tid >> 2;         // finalize-A col 0..31 (tid<128)
  const int pb0  = (tid & 3) * 2;    // finalize-A batch-pair base
  const int fc  = tid >> 3;          // finalize-B col (tid<128 -> 0..15)
  const int fb  = tid & 7;           // finalize-B batch
  const int yb  = tid >> 5;          // y batch 0..7
  const int yq  = tid & 31;          // y k-slice 0..31

  unsigned* ctrA = wsu + CTR_OFF + (bg * 2 + 0) * CTR_STRIDE;
  unsigned* ctrB = wsu + CTR_OFF + (bg * 2 + 1) * CTR_STRIDE;

  __shared__ float bufA[KTOT * RS];  // [k][12]: u_t(k<64) | x or f*x
  __shared__ float pA[4 * 32 * RS];
  __shared__ float pB[4 * 16 * RS];
  __shared__ float rbuf[16 * 8];

  // ---- one-time: weights into registers ----
  float wA[KSL][4];
#pragma unroll
  for (int i = 0; i < KSL; ++i)
#pragma unroll
    for (int m = 0; m < 4; ++m) {
      int c = 4 * cq + m;
      int gcol = (c < 16) ? (16 * cg + c) : (512 + 16 * cg + (c - 16));
      wA[i][m] = kfz[(size_t)(kb + i) * H2_ + gcol];
    }
  float wB[KSL][2];
#pragma unroll
  for (int i = 0; i < KSL; ++i)
#pragma unroll
    for (int m = 0; m < 2; ++m)
      wB[i][m] = kr[(size_t)(kb + i) * H_ + (16 * cg + 2 * cq + m)];
  float wy[16];
#pragma unroll
  for (int i = 0; i < 16; ++i) wy[i] = wout[cg * H_ + (yq + 32 * i)];
  const float by = bout[cg];
  const int fzc = (prow < 16) ? (16 * cg + prow) : (512 + 16 * cg + (prow - 16));
  const float biasA = (tid < 128) ? bfz[fzc] : 0.0f;
  const float biasB = (tid < 128) ? br[16 * cg + fc] : 0.0f;

  float zreg0 = 0.0f, zreg1 = 0.0f, xoldz0 = 0.0f, xoldz1 = 0.0f;

  // u_t=0 into LDS (later steps prefetched during the barrier-B window)
  {
    int k2 = tid & 31, b = tid >> 5;
    float2 uv = *(const float2*)&u[((size_t)(bg * 8 + b) * T_) * IN_ + 2 * k2];
    bufA[(2 * k2) * RS + b] = uv.x;
    bufA[(2 * k2 + 1) * RS + b] = uv.y;
  }

  for (int t = 0; t < T_; ++t) {
    float* xcur = (t & 1) ? xg1 : xg0;
    float* xnxt = (t & 1) ? xg0 : xg1;

    // ---- stage x into bufA (MALL-coherent dwordx4; b128 LDS writes) ----
    {
      const float* s0 = &xcur[(size_t)(bg * H_ + tid) * 8];
      const float* s2 = &xcur[(size_t)(bg * H_ + tid + 256) * 8];
      float4 a, b, c, d;
      gload4x4(s0, s0 + 4, s2, s2 + 4, a, b, c, d);
      *(float4*)&bufA[(64 + tid) * RS] = a;
      *(float4*)&bufA[(64 + tid) * RS + 4] = b;
      *(float4*)&bufA[(64 + tid + 256) * RS] = c;
      *(float4*)&bufA[(64 + tid + 256) * RS + 4] = d;
    }
    __syncthreads();

    // ---- phase A core: fz partials for 4 cols x 8 batches over 18 k ----
    float acc[4][8] = {};
#pragma unroll
    for (int i = 0; i < KSL; ++i) {
      const float* xr = &bufA[(kb + i) * RS];
      float4 x0 = *(const float4*)xr;
      float4 x1 = *(const float4*)(xr + 4);
#pragma unroll
      for (int m = 0; m < 4; ++m) {
        float wv = wA[i][m];
        acc[m][0] += wv * x0.x; acc[m][1] += wv * x0.y;
        acc[m][2] += wv * x0.z; acc[m][3] += wv * x0.w;
        acc[m][4] += wv * x1.x; acc[m][5] += wv * x1.y;
        acc[m][6] += wv * x1.z; acc[m][7] += wv * x1.w;
      }
    }

    // ---- reduce A ----
#pragma unroll
    for (int m = 0; m < 4; ++m)
#pragma unroll
      for (int b = 0; b < 8; ++b) {
        acc[m][b] += __shfl_xor(acc[m][b], 8);
        acc[m][b] += __shfl_xor(acc[m][b], 16);
        acc[m][b] += __shfl_xor(acc[m][b], 32);
      }
    if (g == 0) {
#pragma unroll
      for (int m = 0; m < 4; ++m) {
        float* p = &pA[(w * 32 + 4 * cq + m) * RS];
        *(float4*)p = make_float4(acc[m][0], acc[m][1], acc[m][2], acc[m][3]);
        *(float4*)(p + 4) = make_float4(acc[m][4], acc[m][5], acc[m][6], acc[m][7]);
      }
    }
    __syncthreads();

    // ---- finalize A: sigmoid pairs; packed f*x publish (no drain yet) ----
    if (tid < 128) {
      float s0 = pA[(0 * 32 + prow) * RS + pb0] + pA[(1 * 32 + prow) * RS + pb0] +
                 pA[(2 * 32 + prow) * RS + pb0] + pA[(3 * 32 + prow) * RS + pb0] + biasA;
      float s1 = pA[(0 * 32 + prow) * RS + pb0 + 1] + pA[(1 * 32 + prow) * RS + pb0 + 1] +
                 pA[(2 * 32 + prow) * RS + pb0 + 1] + pA[(3 * 32 + prow) * RS + pb0 + 1] + biasA;
      float sig0 = 1.0f / (1.0f + __expf(-s0));
      float sig1 = 1.0f / (1.0f + __expf(-s1));
      if (prow < 16) {
        int col = 16 * cg + prow;
        float xo0 = bufA[(64 + col) * RS + pb0];
        float xo1 = bufA[(64 + col) * RS + pb0 + 1];
        gpub2f(&xfg[((size_t)bg * H_ + col) * 8 + pb0], sig0 * xo0, sig1 * xo1);
      } else {
        int col = 16 * cg + (prow - 16);
        zreg0 = sig0; zreg1 = sig1;
        xoldz0 = bufA[(64 + col) * RS + pb0];
        xoldz1 = bufA[(64 + col) * RS + pb0 + 1];
      }
    }

    // ---- y_t = x_t @ wout[cg]: covers the in-flight publishes ----
    float yp = 0.0f;
    {
#pragma unroll
      for (int i = 0; i < 16; ++i)
        yp += wy[i] * bufA[(64 + yq + 32 * i) * RS + yb];
      yp += __shfl_xor(yp, 1);  yp += __shfl_xor(yp, 2);
      yp += __shfl_xor(yp, 4);  yp += __shfl_xor(yp, 8);
      yp += __shfl_xor(yp, 16);
    }

    // drain publishes -> block sync -> one counter bump
    asm volatile("s_waitcnt vmcnt(0)" ::: "memory");
    __syncthreads();
    if (tid == 0) gaddu(ctrA, 1u);

    // out-store overlaps the barrier poll
    if (yq == 0)
      out[((size_t)(bg * 8 + yb) * T_ + t) * OUT_ + cg] = yp + by;

    if (!gbar_wait(ctrA, (unsigned)(NCG * (t + 1)), abort_w)) return;

    // ---- stage f*x into bufA (MALL-coherent dwordx4) ----
    {
      const float* s0 = &xfg[(size_t)(bg * H_ + tid) * 8];
      const float* s2 = &xfg[(size_t)(bg * H_ + tid + 256) * 8];
      float4 a, b, c, d;
      gload4x4(s0, s0 + 4, s2, s2 + 4, a, b, c, d);
      *(float4*)&bufA[(64 + tid) * RS] = a;
      *(float4*)&bufA[(64 + tid) * RS + 4] = b;
      *(float4*)&bufA[(64 + tid + 256) * RS] = c;
      *(float4*)&bufA[(64 + tid + 256) * RS + 4] = d;
    }
    __syncthreads();

    // ---- phase B core: r partials for 2 cols x 8 batches ----
    float acc2[2][8] = {};
#pragma unroll
    for (int i = 0; i < KSL; ++i) {
      const float* xr = &bufA[(kb + i) * RS];
      float4 x0 = *(const float4*)xr;
      float4 x1 = *(const float4*)(xr + 4);
#pragma unroll
      for (int m = 0; m < 2; ++m) {
        float wv = wB[i][m];
        acc2[m][0] += wv * x0.x; acc2[m][1] += wv * x0.y;
        acc2[m][2] += wv * x0.z; acc2[m][3] += wv * x0.w;
        acc2[m][4] += wv * x1.x; acc2[m][5] += wv * x1.y;
        acc2[m][6] += wv * x1.z; acc2[m][7] += wv * x1.w;
      }
    }
#pragma unroll
    for (int m = 0; m < 2; ++m)
#pragma unroll
      for (int b = 0; b < 8; ++b) {
        acc2[m][b] += __shfl_xor(acc2[m][b], 8);
        acc2[m][b] += __shfl_xor(acc2[m][b], 16);
        acc2[m][b] += __shfl_xor(acc2[m][b], 32);
      }
    if (g == 0) {
#pragma unroll
      for (int m = 0; m < 2; ++m) {
        float* p = &pB[(w * 16 + 2 * cq + m) * RS];
        *(float4*)p = make_float4(acc2[m][0], acc2[m][1], acc2[m][2], acc2[m][3]);
        *(float4*)(p + 4) = make_float4(acc2[m][4], acc2[m][5], acc2[m][6], acc2[m][7]);
      }
    }
    __syncthreads();

    // ---- finalize B: tanh -> rbuf ----
    if (tid < 128) {
      float s = pB[(0 * 16 + fc) * RS + fb] + pB[(1 * 16 + fc) * RS + fb] +
                pB[(2 * 16 + fc) * RS + fb] + pB[(3 * 16 + fc) * RS + fb] + biasB;
      float e = __expf(2.0f * s);
      rbuf[fc * 8 + fb] = 1.0f - 2.0f / (1.0f + e);
    }
    __syncthreads();

    // ---- update: packed x_next publish (no drain yet) ----
    if (tid >= 64 && tid < 128) {
      int zr = prow - 16;   // 0..15
      float r0 = rbuf[zr * 8 + pb0];
      float r1 = rbuf[zr * 8 + pb0 + 1];
      float xn0 = xoldz0 + zreg0 * (r0 - xoldz0);
      float xn1 = xoldz1 + zreg1 * (r1 - xoldz1);
      gpub2f(&xnxt[((size_t)bg * H_ + 16 * cg + zr) * 8 + pb0], xn0, xn1);
    }

    // ---- prefetch u_{t+1} into LDS: covers the in-flight publishes ----
    if (t + 1 < T_) {
      int k2 = tid & 31, b = tid >> 5;
      float2 uv = *(const float2*)&u[((size_t)(bg * 8 + b) * T_ + (t + 1)) * IN_ + 2 * k2];
      bufA[(2 * k2) * RS + b] = uv.x;
      bufA[(2 * k2 + 1) * RS + b] = uv.y;
    }

    // drain publishes -> block sync -> one counter bump
    asm volatile("s_waitcnt vmcnt(0)" ::: "memory");
    __syncthreads();
    if (tid == 0) gaddu(ctrB, 1u);

    if (!gbar_wait(ctrB, (unsigned)(NCG * (t + 1)), abort_w)) return;
  }
}

extern "C" void kernel_launch(void* const* d_in, const int* in_sizes, int n_in,
                              void* d_out, int out_size, void* d_ws, size_t ws_size,
                              hipStream_t stream) {
  const float* u    = (const float*)d_in[0];
  const float* x0   = (const float*)d_in[1];
  const float* kfz  = (const float*)d_in[2];
  const float* bfz  = (const float*)d_in[3];
  const float* kr   = (const float*)d_in[4];
  const float* br   = (const float*)d_in[5];
  const float* wout = (const float*)d_in[6];
  const float* bout = (const float*)d_in[7];
  float* out = (float*)d_out;
  float* ws  = (float*)d_ws;

  hipLaunchKernelGGL(gru_init, dim3(64), dim3(256), 0, stream, ws, x0);
  hipLaunchKernelGGL(gru_main, dim3(NBG * NCG), dim3(NTHR), 0, stream,
                     u, kfz, bfz, kr, br, wout, bout, out, ws);
}

// Round 7
// 13694.441 us; speedup vs baseline: 2.8238x; 1.1399x over previous
//
#include <hip/hip_runtime.h>
#include <hip/hip_fp16.h>
#include <stdint.h>

// Problem dims
#define B_    64
#define T_    2048
#define IN_   64
#define H_    512
#define H2_   1024
#define OUT_  32
#define KTOT  576          // IN_ + H_

// Grid: 256 blocks = 8 batch-groups x 32 col-groups, 256 threads.
// (512-thread fusion FAILED in round 5: VGPR cap 128 -> weight spill.
//  Deferred-bump FAILED in round 6: bump behind u-prefetch HBM load ->
//  global critical path +1.7ms. Order must be: publish->drain->sync->bump,
//  independent work AFTER the bump.)
#define NBG   8
#define NCG   32
#define NTHR  256
#define BPG   8            // batches per group
#define KSL   18           // k per slice (32 slices x 18 = 576)
#define RS    12           // bufA row stride in floats

// ws layout (32-bit words)
// Barriers: one aggregated u32 counter per (bg, phase), 4KB-strided so the 16
// hot words map to distinct channels (round-4 win: 15.3 -> 13.9 ms).
// Exchange slabs are FP16: [bg][col 512][batch 8] halves = 8KB per bg slab
// (halves the synchronized post-barrier MALL stage burst vs f32).
#define ABORT_IDX   0
#define CTR_OFF     1024                 // first counter, word offset (4KB)
#define CTR_STRIDE  1024                 // 4KB between counters
#define NCTR        (NBG * 2)            // 16 counters
#define BUF_BASE    (CTR_OFF + NCTR * CTR_STRIDE)   // 17408 (64B-aligned)
#define XSLABW      16384    // 32-bit words per fp16 slab: 8*512*8*2B / 4

// ---- fp16 pack/unpack ----
__device__ __forceinline__ unsigned f2h2(float a, float b) {
  __half2 h = __floats2half2_rn(a, b);   // lo = a, hi = b
  unsigned r; __builtin_memcpy(&r, &h, 4); return r;
}
__device__ __forceinline__ float2 h2f2(unsigned u) {
  __half2 h; __builtin_memcpy(&h, &u, 4);
  return __half22float2(h);              // x = lo, y = hi
}

// ---- MALL-resident exchange primitives ----
// Publish one packed (batch b, b+1) fp16 pair: 4B atomic swap, sc1 -> executed
// AT the MALL (line stays MALL-dirty). Per-thread drain INSIDE (round-4 rule:
// bump must follow drain immediately; independent work goes after the bump).
__device__ __forceinline__ void gpubh(unsigned* p, unsigned v) {
  asm volatile("global_atomic_swap %0, %1, off sc1\n\ts_waitcnt vmcnt(0)"
               :: "v"(p), "v"(v) : "memory");
}
// Counter bump: fire-and-forget one-way add at the MALL.
__device__ __forceinline__ void gaddu(unsigned* p, unsigned v) {
  asm volatile("global_atomic_add %0, %1, off sc1"
               :: "v"(p), "v"(v) : "memory");
}
// Coherent 4B poll load (bypasses stale L1/L2, reads the MALL).
__device__ __forceinline__ unsigned gpollu(const unsigned* p) {
  unsigned v;
  asm volatile("global_load_dword %0, %1, off sc0 sc1\n\ts_waitcnt vmcnt(0)"
               : "=v"(v) : "v"(p) : "memory");
  return v;
}
// Consume: MALL-coherent 16B loads (8 fp16 = one col's 8 batches each),
// 2 in flight, one wait -> one latency exposure per stage.
__device__ __forceinline__ void gload2(const unsigned* p0, const unsigned* p1,
                                       uint4& a, uint4& b) {
  asm volatile(
      "global_load_dwordx4 %0, %2, off sc0 sc1\n\t"
      "global_load_dwordx4 %1, %3, off sc0 sc1\n\t"
      "s_waitcnt vmcnt(0)"
      : "=&v"(a), "=&v"(b)
      : "v"(p0), "v"(p1)
      : "memory");
}

__global__ __launch_bounds__(256) void gru_init(float* ws, const float* __restrict__ x0) {
  int i = blockIdx.x * blockDim.x + threadIdx.x;
  int stride = gridDim.x * blockDim.x;
  unsigned* w = (unsigned*)ws;
  for (int k = i; k < BUF_BASE; k += stride) w[k] = 0u;   // abort + counters
  // xg0 slab (fp16): word p = [bg][col][batch-pair]
  unsigned* xh = w + BUF_BASE;
  for (int p = i; p < NBG * H_ * 4; p += stride) {
    int bg = p >> 11, col = (p >> 2) & (H_ - 1), f2 = p & 3;
    float v0 = x0[(bg * 8 + 2 * f2) * H_ + col];
    float v1 = x0[(bg * 8 + 2 * f2 + 1) * H_ + col];
    xh[p] = f2h2(v0, v1);
  }
}

// Wait: ONE lane polls ONE 4KB-isolated counter word until it reaches target.
__device__ __forceinline__ bool gbar_wait(unsigned* ctr, unsigned target,
                                          unsigned* abort_w) {
  __shared__ int s_ok;
  if (threadIdx.x == 0) {
    int ok = 1;
    int polls = 0;
    while (gpollu(ctr) < target) {
      __builtin_amdgcn_s_sleep(1);
      if ((++polls & 255) == 0) {
        if (__hip_atomic_load(abort_w, __ATOMIC_RELAXED, __HIP_MEMORY_SCOPE_AGENT) != 0u ||
            polls > 2000000) {
          __hip_atomic_store(abort_w, 1u, __ATOMIC_RELAXED, __HIP_MEMORY_SCOPE_AGENT);
          ok = 0;
          break;
        }
      }
    }
    s_ok = ok;
  }
  __syncthreads();
  __atomic_signal_fence(__ATOMIC_ACQUIRE);  // compiler reordering guard only
  return s_ok != 0;
}

__global__ __launch_bounds__(NTHR, 1) void gru_main(
    const float* __restrict__ u, const float* __restrict__ kfz,
    const float* __restrict__ bfz, const float* __restrict__ kr,
    const float* __restrict__ br, const float* __restrict__ wout,
    const float* __restrict__ bout, float* __restrict__ out, float* ws) {
  unsigned* wsu = (unsigned*)ws;
  unsigned* abort_w = wsu + ABORT_IDX;
  unsigned* xg0 = wsu + BUF_BASE;
  unsigned* xg1 = xg0 + XSLABW;
  unsigned* xfg = xg1 + XSLABW;

  const int bg  = blockIdx.x & 7;
  const int cg  = blockIdx.x >> 3;   // column group 0..31
  const int tid = threadIdx.x;
  const int w   = tid >> 6;          // wave 0..3
  const int l   = tid & 63;
  const int cq  = l & 7;             // col-quad 0..7
  const int g   = l >> 3;            // in-wave k-slice 0..7
  const int kb  = (w * 8 + g) * KSL; // this thread's k base (18 k's)
  const int fc  = tid >> 3;          // finalize col 0..31
  const int fb  = tid & 7;           // finalize batch 0..7
  const int yb  = tid >> 5;          // y batch 0..7
  const int yq  = tid & 31;          // y k-slice 0..31

  unsigned* ctrA = wsu + CTR_OFF + (bg * 2 + 0) * CTR_STRIDE;
  unsigned* ctrB = wsu + CTR_OFF + (bg * 2 + 1) * CTR_STRIDE;

  __shared__ float bufA[KTOT * RS];  // [k][12]: u_t(k<64) | x or f*x
  __shared__ float pA[4 * 32 * RS];
  __shared__ float pB[4 * 16 * RS];
  __shared__ float rbuf[16 * 8];

  // ---- one-time: weights into registers ----
  float wA[KSL][4];
#pragma unroll
  for (int i = 0; i < KSL; ++i)
#pragma unroll
    for (int m = 0; m < 4; ++m) {
      int c = 4 * cq + m;
      int gcol = (c < 16) ? (16 * cg + c) : (512 + 16 * cg + (c - 16));
      wA[i][m] = kfz[(size_t)(kb + i) * H2_ + gcol];
    }
  float wB[KSL][2];
#pragma unroll
  for (int i = 0; i < KSL; ++i)
#pragma unroll
    for (int m = 0; m < 2; ++m)
      wB[i][m] = kr[(size_t)(kb + i) * H_ + (16 * cg + 2 * cq + m)];
  float wy[16];
#pragma unroll
  for (int i = 0; i < 16; ++i) wy[i] = wout[cg * H_ + (yq + 32 * i)];
  const float by = bout[cg];
  const int fzc = (fc < 16) ? (16 * cg + fc) : (512 + 16 * cg + (fc - 16));
  const float biasA = bfz[fzc];
  const float biasB = (tid < 128) ? br[16 * cg + fc] : 0.0f;

  float zreg = 0.0f, xoldz = 0.0f;

  // u_t=0 into LDS (later steps prefetched during barrier-B window)
  {
    int k2 = tid & 31, b = tid >> 5;
    float2 uv = *(const float2*)&u[((size_t)(bg * 8 + b) * T_) * IN_ + 2 * k2];
    bufA[(2 * k2) * RS + b] = uv.x;
    bufA[(2 * k2 + 1) * RS + b] = uv.y;
  }

  for (int t = 0; t < T_; ++t) {
    unsigned* xcur = (t & 1) ? xg1 : xg0;
    unsigned* xnxt = (t & 1) ? xg0 : xg1;

    // ---- stage x into bufA (fp16 slab: 2 cols/thread, cvt, b128 writes) ----
    {
      const unsigned* s0 = xcur + ((size_t)(bg * H_) + tid) * 4;
      const unsigned* s1 = xcur + ((size_t)(bg * H_) + tid + 256) * 4;
      uint4 a, b;
      gload2(s0, s1, a, b);
      float2 c0 = h2f2(a.x), c1 = h2f2(a.y), c2 = h2f2(a.z), c3 = h2f2(a.w);
      *(float4*)&bufA[(64 + tid) * RS]     = make_float4(c0.x, c0.y, c1.x, c1.y);
      *(float4*)&bufA[(64 + tid) * RS + 4] = make_float4(c2.x, c2.y, c3.x, c3.y);
      float2 d0 = h2f2(b.x), d1 = h2f2(b.y), d2 = h2f2(b.z), d3 = h2f2(b.w);
      *(float4*)&bufA[(64 + tid + 256) * RS]     = make_float4(d0.x, d0.y, d1.x, d1.y);
      *(float4*)&bufA[(64 + tid + 256) * RS + 4] = make_float4(d2.x, d2.y, d3.x, d3.y);
    }
    __syncthreads();

    // ---- phase A core: fz partials for 4 cols x 8 batches over 18 k ----
    float acc[4][8] = {};
#pragma unroll
    for (int i = 0; i < KSL; ++i) {
      const float* xr = &bufA[(kb + i) * RS];
      float4 x0 = *(const float4*)xr;
      float4 x1 = *(const float4*)(xr + 4);
#pragma unroll
      for (int m = 0; m < 4; ++m) {
        float wv = wA[i][m];
        acc[m][0] += wv * x0.x; acc[m][1] += wv * x0.y;
        acc[m][2] += wv * x0.z; acc[m][3] += wv * x0.w;
        acc[m][4] += wv * x1.x; acc[m][5] += wv * x1.y;
        acc[m][6] += wv * x1.z; acc[m][7] += wv * x1.w;
      }
    }

    // ---- reduce A ----
#pragma unroll
    for (int m = 0; m < 4; ++m)
#pragma unroll
      for (int b = 0; b < 8; ++b) {
        acc[m][b] += __shfl_xor(acc[m][b], 8);
        acc[m][b] += __shfl_xor(acc[m][b], 16);
        acc[m][b] += __shfl_xor(acc[m][b], 32);
      }
    if (g == 0) {
#pragma unroll
      for (int m = 0; m < 4; ++m) {
        float* p = &pA[(w * 32 + 4 * cq + m) * RS];
        *(float4*)p = make_float4(acc[m][0], acc[m][1], acc[m][2], acc[m][3]);
        *(float4*)(p + 4) = make_float4(acc[m][4], acc[m][5], acc[m][6], acc[m][7]);
      }
    }
    __syncthreads();

    // ---- finalize A: sigmoid; publish packed fp16 f*x pairs; stash z ----
    {
      float s = pA[(0 * 32 + fc) * RS + fb] + pA[(1 * 32 + fc) * RS + fb] +
                pA[(2 * 32 + fc) * RS + fb] + pA[(3 * 32 + fc) * RS + fb] + biasA;
      float sig = 1.0f / (1.0f + __expf(-s));
      if (fc < 16) {
        float xo = bufA[(64 + 16 * cg + fc) * RS + fb];
        float v = sig * xo;
        float v1 = __shfl_xor(v, 1);      // neighbor batch's value
        if ((tid & 1) == 0) {
          unsigned* p = xfg + ((size_t)(bg * H_) + 16 * cg + fc) * 4 + (fb >> 1);
          gpubh(p, f2h2(v, v1));          // swap + drain (round-4 rule)
        }
      } else {
        zreg = sig;
        xoldz = bufA[(64 + 16 * cg + (fc - 16)) * RS + fb];
      }
    }

    // publishes drained per-thread -> sync -> bump (earliest possible)
    __syncthreads();
    if (tid == 0) gaddu(ctrA, 1u);

    // ---- y_t = x_t @ wout[cg]: overlaps the barrier poll ----
    {
      float yp = 0.0f;
#pragma unroll
      for (int i = 0; i < 16; ++i)
        yp += wy[i] * bufA[(64 + yq + 32 * i) * RS + yb];
      yp += __shfl_xor(yp, 1);  yp += __shfl_xor(yp, 2);
      yp += __shfl_xor(yp, 4);  yp += __shfl_xor(yp, 8);
      yp += __shfl_xor(yp, 16);
      if (yq == 0)
        out[((size_t)(bg * 8 + yb) * T_ + t) * OUT_ + cg] = yp + by;
    }

    if (!gbar_wait(ctrA, (unsigned)(NCG * (t + 1)), abort_w)) return;

    // ---- stage f*x into bufA (fp16 slab) ----
    {
      const unsigned* s0 = xfg + ((size_t)(bg * H_) + tid) * 4;
      const unsigned* s1 = xfg + ((size_t)(bg * H_) + tid + 256) * 4;
      uint4 a, b;
      gload2(s0, s1, a, b);
      float2 c0 = h2f2(a.x), c1 = h2f2(a.y), c2 = h2f2(a.z), c3 = h2f2(a.w);
      *(float4*)&bufA[(64 + tid) * RS]     = make_float4(c0.x, c0.y, c1.x, c1.y);
      *(float4*)&bufA[(64 + tid) * RS + 4] = make_float4(c2.x, c2.y, c3.x, c3.y);
      float2 d0 = h2f2(b.x), d1 = h2f2(b.y), d2 = h2f2(b.z), d3 = h2f2(b.w);
      *(float4*)&bufA[(64 + tid + 256) * RS]     = make_float4(d0.x, d0.y, d1.x, d1.y);
      *(float4*)&bufA[(64 + tid + 256) * RS + 4] = make_float4(d2.x, d2.y, d3.x, d3.y);
    }
    __syncthreads();

    // ---- phase B core: r partials for 2 cols x 8 batches ----
    float acc2[2][8] = {};
#pragma unroll
    for (int i = 0; i < KSL; ++i) {
      const float* xr = &bufA[(kb + i) * RS];
      float4 x0 = *(const float4*)xr;
      float4 x1 = *(const float4*)(xr + 4);
#pragma unroll
      for (int m = 0; m < 2; ++m) {
        float wv = wB[i][m];
        acc2[m][0] += wv * x0.x; acc2[m][1] += wv * x0.y;
        acc2[m][2] += wv * x0.z; acc2[m][3] += wv * x0.w;
        acc2[m][4] += wv * x1.x; acc2[m][5] += wv * x1.y;
        acc2[m][6] += wv * x1.z; acc2[m][7] += wv * x1.w;
      }
    }
#pragma unroll
    for (int m = 0; m < 2; ++m)
#pragma unroll
      for (int b = 0; b < 8; ++b) {
        acc2[m][b] += __shfl_xor(acc2[m][b], 8);
        acc2[m][b] += __shfl_xor(acc2[m][b], 16);
        acc2[m][b] += __shfl_xor(acc2[m][b], 32);
      }
    if (g == 0) {
#pragma unroll
      for (int m = 0; m < 2; ++m) {
        float* p = &pB[(w * 16 + 2 * cq + m) * RS];
        *(float4*)p = make_float4(acc2[m][0], acc2[m][1], acc2[m][2], acc2[m][3]);
        *(float4*)(p + 4) = make_float4(acc2[m][4], acc2[m][5], acc2[m][6], acc2[m][7]);
      }
    }
    __syncthreads();

    // ---- finalize B: tanh -> rbuf ----
    if (tid < 128) {
      float s = pB[(0 * 16 + fc) * RS + fb] + pB[(1 * 16 + fc) * RS + fb] +
                pB[(2 * 16 + fc) * RS + fb] + pB[(3 * 16 + fc) * RS + fb] + biasB;
      float e = __expf(2.0f * s);
      rbuf[fc * 8 + fb] = 1.0f - 2.0f / (1.0f + e);
    }
    __syncthreads();

    // ---- update: x_next = x + z*(r - x); packed fp16 publish ----
    if (tid >= 128) {
      float r = rbuf[(fc - 16) * 8 + fb];
      float xn = xoldz + zreg * (r - xoldz);
      float xn1 = __shfl_xor(xn, 1);
      if ((tid & 1) == 0) {
        unsigned* p = xnxt + ((size_t)(bg * H_) + 16 * cg + (fc - 16)) * 4 + (fb >> 1);
        gpubh(p, f2h2(xn, xn1));          // swap + drain
      }
    }

    // publishes drained -> sync -> bump; u-prefetch AFTER the bump
    __syncthreads();
    if (tid == 0) gaddu(ctrB, 1u);

    // ---- prefetch u_{t+1} into LDS while barrier-2 resolves ----
    if (t + 1 < T_) {
      int k2 = tid & 31, b = tid >> 5;
      float2 uv = *(const float2*)&u[((size_t)(bg * 8 + b) * T_ + (t + 1)) * IN_ + 2 * k2];
      bufA[(2 * k2) * RS + b] = uv.x;
      bufA[(2 * k2 + 1) * RS + b] = uv.y;
    }

    if (!gbar_wait(ctrB, (unsigned)(NCG * (t + 1)), abort_w)) return;
  }
}

extern "C" void kernel_launch(void* const* d_in, const int* in_sizes, int n_in,
                              void* d_out, int out_size, void* d_ws, size_t ws_size,
                              hipStream_t stream) {
  const float* u    = (const float*)d_in[0];
  const float* x0   = (const float*)d_in[1];
  const float* kfz  = (const float*)d_in[2];
  const float* bfz  = (const float*)d_in[3];
  const float* kr   = (const float*)d_in[4];
  const float* br   = (const float*)d_in[5];
  const float* wout = (const float*)d_in[6];
  const float* bout = (const float*)d_in[7];
  float* out = (float*)d_out;
  float* ws  = (float*)d_ws;

  hipLaunchKernelGGL(gru_init, dim3(64), dim3(256), 0, stream, ws, x0);
  hipLaunchKernelGGL(gru_main, dim3(NBG * NCG), dim3(NTHR), 0, stream,
                     u, kfz, bfz, kr, br, wout, bout, out, ws);
}